// Round 2
// baseline (151.580 us; speedup 1.0000x reference)
//
#include <hip/hip_runtime.h>
#include <hip/hip_bf16.h>

// ConvCaps EM-routing, MI355X. B=8, 7x7 out, 288 in-votes, 32 out-caps, 16 pose.
// 392 independent routing problems (one block each, 256 threads).
// I/O is FP32 (reference dtypes). Votes (576KB/n fp32) are recomputed per pass
// from LDS-resident poses + L2-resident weights (576 KB, shared by all blocks).

namespace {

constexpr int NKK = 288;                 // K*K*IN_CAPS
constexpr float EPSF = 1e-8f;
constexpr float LN2PI = 1.8378770664093453f;

__global__ __launch_bounds__(256)
void caps_em_kernel(const float* __restrict__ x,
                    const float* __restrict__ Wg,
                    const float* __restrict__ bu,
                    const float* __restrict__ ba,
                    float* __restrict__ out)
{
    // LDS: 18432 + 1152 + 38016 + 17408 + 2048 + 2048 + 640 = 79744 B -> 2 blocks/CU
    __shared__ float p4[NKK * 16];       // pose fragments [k*16+p]
    __shared__ float aIn[NKK];           // input activations
    __shared__ float rbuf[NKK * 33];     // r / r_hat / ln_ap, padded stride 33
    __shared__ float scr[8 * 544];       // partial-reduce scratch, stride 17 per (o) row
    __shared__ float meanS[512];         // mean[o*16+p]
    __shared__ float i2vS[512];          // 1/(2*std^2)
    __shared__ float rsumS[32];
    __shared__ float invrsS[32];
    __shared__ float s1S[32];            // sum_k r_prob = rs/(rs+eps)
    __shared__ float actS[32];
    __shared__ float baseS[32];          // -sum_p log std - 8*ln(2pi) + log(act)

    const int n = blockIdx.x;
    const int t = threadIdx.x;

    // ---- gather poses: flat view of tiled (B,kh,kw,oh,ow,512) ----
    for (int idx = t; idx < NKK * 16; idx += 256) {
        unsigned g = (unsigned)n * 4608u + (unsigned)idx;
        unsigned c = g & 511u, rest = g >> 9;
        unsigned ow = rest % 7u; rest /= 7u;
        unsigned oh = rest % 7u; rest /= 7u;
        unsigned kw = rest % 3u; rest /= 3u;
        unsigned kh = rest % 3u;
        unsigned b  = rest / 3u;
        p4[idx] = x[((b*16u + 2u*oh + kh)*16u + 2u*ow + kw)*544u + c];
    }
    // ---- gather acts: flat view of tiled (B,kh,kw,oh,ow,32) ----
    for (int idx = t; idx < NKK; idx += 256) {
        unsigned g = (unsigned)n * 288u + (unsigned)idx;
        unsigned c = g & 31u, rest = g >> 5;
        unsigned ow = rest % 7u; rest /= 7u;
        unsigned oh = rest % 7u; rest /= 7u;
        unsigned kw = rest % 3u; rest /= 3u;
        unsigned kh = rest % 3u;
        unsigned b  = rest / 3u;
        aIn[idx] = x[((b*16u + 2u*oh + kh)*16u + 2u*ow + kw)*544u + 512u + c];
    }
    for (int idx = t; idx < NKK * 32; idx += 256)
        rbuf[(idx >> 5)*33 + (idx & 31)] = 0.03125f;   // 1/OUT_CAPS
    __syncthreads();

    const int o  = t & 31;    // out-cap owned by this thread
    const int kc = t >> 5;    // k-chunk (8 chunks of 36)

    float lam = 1.0e-3f;
    float Sv[16], Sv2[16];

    for (int it = 0; it < 3; ++it) {
        lam += 1.0e-4f;

        // ---- M1: r_hat[k,o] = r*a / (sum_o(r)*a + eps) ----
        for (int k = t; k < NKK; k += 256) {
            const float a = aIn[k];
            float s = 0.f;
            #pragma unroll
            for (int oo = 0; oo < 32; ++oo) s += rbuf[k*33 + oo];
            const float sc = a / (s * a + EPSF);
            #pragma unroll
            for (int oo = 0; oo < 32; ++oo) rbuf[k*33 + oo] *= sc;
        }
        __syncthreads();

        // ---- r_sum[o] over k ----
        {
            float s = 0.f;
            for (int kk = 0; kk < 36; ++kk) s += rbuf[(kc*36 + kk)*33 + o];
            scr[kc*32 + o] = s;
        }
        __syncthreads();
        if (t < 32) {
            float rs = 0.f;
            #pragma unroll
            for (int q = 0; q < 8; ++q) rs += scr[q*32 + t];
            rsumS[t] = rs;
            const float inv = 1.0f / (rs + EPSF);
            invrsS[t] = inv;
            s1S[t] = rs * inv;
        }
        __syncthreads();

        // ---- M2: one-pass weighted moments of recomputed votes ----
        #pragma unroll
        for (int p = 0; p < 16; ++p) { Sv[p] = 0.f; Sv2[p] = 0.f; }
        {
            const float irs = invrsS[o];
            for (int kk = 0; kk < 36; ++kk) {
                const int k = kc*36 + kk;
                const float w = rbuf[k*33 + o] * irs;   // r_prob
                float P[16], Wl[16];
                #pragma unroll
                for (int p = 0; p < 16; p += 4) {
                    const float4 v4 = *(const float4*)&p4[k*16 + p];
                    P[p] = v4.x; P[p+1] = v4.y; P[p+2] = v4.z; P[p+3] = v4.w;
                    const float4 w4 = *(const float4*)&Wg[(k*32 + o)*16 + p];
                    Wl[p] = w4.x; Wl[p+1] = w4.y; Wl[p+2] = w4.z; Wl[p+3] = w4.w;
                }
                #pragma unroll
                for (int i = 0; i < 4; ++i) {
                    #pragma unroll
                    for (int m = 0; m < 4; ++m) {
                        float v = P[i*4] * Wl[m];
                        v = fmaf(P[i*4+1], Wl[4+m],  v);
                        v = fmaf(P[i*4+2], Wl[8+m],  v);
                        v = fmaf(P[i*4+3], Wl[12+m], v);
                        const float wv = w * v;
                        Sv [i*4+m] += wv;
                        Sv2[i*4+m]  = fmaf(wv, v, Sv2[i*4+m]);
                    }
                }
            }
        }
        #pragma unroll
        for (int p = 0; p < 16; ++p) scr[(kc*32 + o)*17 + p] = Sv[p];
        __syncthreads();
        for (int op = t; op < 512; op += 256) {
            const int oo = op >> 4, pp = op & 15;
            float s = 0.f;
            #pragma unroll
            for (int q = 0; q < 8; ++q) s += scr[q*544 + oo*17 + pp];
            meanS[op] = s;
        }
        __syncthreads();
        #pragma unroll
        for (int p = 0; p < 16; ++p) scr[(kc*32 + o)*17 + p] = Sv2[p];
        __syncthreads();
        for (int op = t; op < 512; op += 256) {
            const int oo = op >> 4, pp = op & 15;
            float s = 0.f;
            #pragma unroll
            for (int q = 0; q < 8; ++q) s += scr[q*544 + oo*17 + pp];
            const float m = meanS[op];
            // sum r_prob*(v-m)^2 = E[v^2] - m^2*(2 - S1)   (S1 = sum r_prob)
            float var = s - m*m*(2.0f - s1S[oo]);
            var = fmaxf(var, 0.0f) + EPSF;                // std^2 (+eps inside sqrt)
            i2vS[op] = 0.5f / var;                         // 1/(2 std^2)
            scr[oo*17 + pp] = 0.5f * __logf(var);          // log(std), reuse q=0 slot (owned)
        }
        __syncthreads();
        if (t < 32) {
            float lsum = 0.f;
            #pragma unroll
            for (int p = 0; p < 16; ++p) lsum += scr[t*17 + p];
            const float rs   = rsumS[t];
            const float cost = (16.0f * bu[t] + lsum) * rs;
            const float ao   = 1.0f / (1.0f + __expf(-lam * (ba[t] - cost)));
            actS[t]  = ao;
            baseS[t] = -lsum - 8.0f*LN2PI + __logf(ao);
        }
        __syncthreads();

        if (it == 2) break;

        // ---- E-step: ln_ap[k,o] = base[o] - sum_p (v-mean)^2/(2 std^2) ----
        {
            float M[16], I[16];
            #pragma unroll
            for (int p = 0; p < 16; ++p) { M[p] = meanS[o*16 + p]; I[p] = i2vS[o*16 + p]; }
            const float base = baseS[o];
            for (int kk = 0; kk < 36; ++kk) {
                const int k = kc*36 + kk;
                float P[16], Wl[16];
                #pragma unroll
                for (int p = 0; p < 16; p += 4) {
                    const float4 v4 = *(const float4*)&p4[k*16 + p];
                    P[p] = v4.x; P[p+1] = v4.y; P[p+2] = v4.z; P[p+3] = v4.w;
                    const float4 w4 = *(const float4*)&Wg[(k*32 + o)*16 + p];
                    Wl[p] = w4.x; Wl[p+1] = w4.y; Wl[p+2] = w4.z; Wl[p+3] = w4.w;
                }
                float sacc = 0.f;
                #pragma unroll
                for (int i = 0; i < 4; ++i) {
                    #pragma unroll
                    for (int m = 0; m < 4; ++m) {
                        float v = P[i*4] * Wl[m];
                        v = fmaf(P[i*4+1], Wl[4+m],  v);
                        v = fmaf(P[i*4+2], Wl[8+m],  v);
                        v = fmaf(P[i*4+3], Wl[12+m], v);
                        const float d = v - M[i*4+m];
                        sacc = fmaf(d*d, I[i*4+m], sacc);
                    }
                }
                rbuf[k*33 + o] = base - sacc;
            }
        }
        __syncthreads();
        // softmax over o per k -> new r
        for (int k = t; k < NKK; k += 256) {
            float mx = -3.0e38f;
            #pragma unroll
            for (int oo = 0; oo < 32; ++oo) mx = fmaxf(mx, rbuf[k*33 + oo]);
            float ssum = 0.f;
            #pragma unroll
            for (int oo = 0; oo < 32; ++oo) {
                const float e = __expf(rbuf[k*33 + oo] - mx);
                rbuf[k*33 + oo] = e;
                ssum += e;
            }
            const float inv = 1.0f / ssum;
            #pragma unroll
            for (int oo = 0; oo < 32; ++oo) rbuf[k*33 + oo] *= inv;
        }
        __syncthreads();
    }

    // ---- output: [mean(512) | act(32)] per n, contiguous ----
    for (int idx = t; idx < 544; idx += 256) {
        const float v = (idx < 512) ? meanS[idx] : actS[idx - 512];
        out[n*544 + idx] = v;
    }
}

} // namespace

extern "C" void kernel_launch(void* const* d_in, const int* in_sizes, int n_in,
                              void* d_out, int out_size, void* d_ws, size_t ws_size,
                              hipStream_t stream) {
    (void)in_sizes; (void)n_in; (void)out_size; (void)d_ws; (void)ws_size;
    const float* x  = (const float*)d_in[0];
    const float* W  = (const float*)d_in[1];
    const float* bu = (const float*)d_in[2];
    const float* ba = (const float*)d_in[3];
    float* out = (float*)d_out;
    caps_em_kernel<<<dim3(392), dim3(256), 0, stream>>>(x, W, bu, ba, out);
}